// Round 3
// baseline (3221.475 us; speedup 1.0000x reference)
//
#include <hip/hip_runtime.h>
#include <math.h>

#define Tt 4096
#define NB 16

#define CLN2PI 1.8378770664093453f   // ln(2*pi)

// ws layout (float offsets)
#define OFF_W    0         // 131072  W = L^-1 per state (row-major, upper zeros)
#define OFF_D    131072    // 2048    d = W*mu
#define OFF_CST  133120    // 32      F*ln2pi + logdet  (nats)
#define OFF_EV   133152    // 16      evidence per batch (fp32 nats)
#define OFF_LB   133184    // 2097152 logB nats [b][t][s]
#define OFF_BET  2230336   // 2097152 beta  nats [b][t][s]
// total 4327488 floats = 17.3 MB

__device__ __forceinline__ float rdlane(float x, int l) {
  return __int_as_float(__builtin_amdgcn_readlane(__float_as_int(x), l));
}

// ---------------- K2: per-state Cholesky, W = L^-1, d = W*mu, cst ----------------
__global__ __launch_bounds__(64) void k_chol(const float* __restrict__ covs,
                                             const float* __restrict__ means,
                                             float* __restrict__ ws) {
  __shared__ float Am[64][65];
  __shared__ float Wl[64][65];
  int s = blockIdx.x, j = threadIdx.x;
  for (int r = 0; r < 64; ++r) {
    Am[r][j] = covs[((size_t)s * 64 + r) * 64 + j];
    Wl[r][j] = 0.f;
  }
  __syncthreads();
  for (int k = 0; k < 64; ++k) {
    float diag = sqrtf(Am[k][k]);
    float col = (j > k) ? Am[j][k] / diag : 0.f;
    __syncthreads();
    if (j == k) Am[k][k] = diag;
    if (j > k)  Am[j][k] = col;
    __syncthreads();
    if (j > k) {
      for (int g = k + 1; g <= j; ++g) Am[j][g] -= col * Am[g][k];
    }
    __syncthreads();
  }
  {
    int c = j;
    Wl[c][c] = 1.0f / Am[c][c];
    for (int f = c + 1; f < 64; ++f) {
      float ssum = 0.f;
      for (int g = c; g < f; ++g) ssum += Am[f][g] * Wl[g][c];
      Wl[f][c] = -ssum / Am[f][f];
    }
  }
  __syncthreads();
  for (int r = 0; r < 64; ++r)
    ws[OFF_W + ((size_t)s * 64 + r) * 64 + j] = Wl[r][j];
  {
    float acc = 0.f;
    for (int g = 0; g < 64; ++g) acc += Wl[j][g] * means[s * 64 + g];
    ws[OFF_D + s * 64 + j] = acc;
  }
  if (j == 0) {
    float logdet = 0.f;
    for (int k = 0; k < 64; ++k) logdet += __logf(Am[k][k]);
    logdet *= 2.0f;
    ws[OFF_CST + s] = 64.0f * CLN2PI + logdet;
  }
}

// ---------------- K3: emission logB (nats) ----------------
__global__ __launch_bounds__(64) void k_emis(const float* __restrict__ x,
                                             const float* __restrict__ wsr,
                                             float* __restrict__ lb) {
  const float* W = wsr + OFF_W;
  const float* D = wsr + OFF_D;
  const float* C = wsr + OFF_CST;
  int bx = blockIdx.x;
  int sgrp = bx & 3;
  int pt = (bx >> 2) * 64 + threadIdx.x;
  const float* xr = x + (size_t)pt * 64;
  float xv[64];
#pragma unroll
  for (int c = 0; c < 16; ++c) {
    float4 q = ((const float4*)xr)[c];
    xv[4 * c + 0] = q.x; xv[4 * c + 1] = q.y;
    xv[4 * c + 2] = q.z; xv[4 * c + 3] = q.w;
  }
#pragma unroll 1
  for (int si = 0; si < 8; ++si) {
    int s = sgrp * 8 + si;
    const float* Ws = W + (size_t)s * 4096;
    const float* Ds = D + s * 64;
    float maha = 0.f;
#pragma unroll
    for (int f = 0; f < 64; ++f) {
      float z = -Ds[f];
#pragma unroll
      for (int ch = 0; ch < 4; ++ch) {
        if (ch <= (f >> 4)) {
#pragma unroll
          for (int gg = 0; gg < 16; ++gg) {
            int g = ch * 16 + gg;
            z = fmaf(Ws[f * 64 + g], xv[g], z);
          }
        }
      }
      maha = fmaf(z, z, maha);
    }
    lb[(size_t)pt * 32 + s] = -0.5f * (maha + C[s]);
  }
}

// np-pairwise-order sum of 32 (matches numpy's 8-accumulator pairwise order)
__device__ __forceinline__ float npsum32(const float* z) {
  float r[8];
#pragma unroll
  for (int k = 0; k < 8; ++k)
    r[k] = ((z[k] + z[k + 8]) + z[k + 16]) + z[k + 24];
  return ((r[0] + r[1]) + (r[2] + r[3])) + ((r[4] + r[5]) + (r[6] + r[7]));
}
// exact max of 32 (order-independent), balanced tree
__device__ __forceinline__ float max32(const float* z) {
  float t16[16];
#pragma unroll
  for (int k = 0; k < 16; ++k) t16[k] = fmaxf(z[k], z[k + 16]);
  float t8[8];
#pragma unroll
  for (int k = 0; k < 8; ++k) t8[k] = fmaxf(t16[k], t16[k + 8]);
  float t4[4];
#pragma unroll
  for (int k = 0; k < 4; ++k) t4[k] = fmaxf(t8[k], t8[k + 4]);
  float t2a = fmaxf(t4[0], t4[2]), t2b = fmaxf(t4[1], t4[3]);
  return fmaxf(t2a, t2b);
}

// ---------------- K4: forward/backward, fp32 nats, np-matched ops ----------------
// 1 wave per (batch, dir). lane j (&31) owns state j; halves duplicate.
__global__ __launch_bounds__(64) void k_fb(const float* __restrict__ logA,
                                           const float* __restrict__ logpi,
                                           float* __restrict__ ws,
                                           float* __restrict__ out) {
  const float* lbg = ws + OFF_LB;
  float* bet = ws + OFF_BET;
  float* ev  = ws + OFF_EV;
  int chain = blockIdx.x;
  int b   = chain & 15;
  int dir = chain >> 4;
  int lane = threadIdx.x;
  int j = lane & 31;
  const float* lb = lbg + (size_t)b * Tt * 32;
  float z[32];
  if (dir == 0) {
    float acol[32];                      // A[i][j] for all i
#pragma unroll
    for (int i = 0; i < 32; ++i) acol[i] = logA[i * 32 + j];
    float* ao = out + (size_t)b * Tt * 32;
    float a = logpi[j] + lb[j];          // alpha[0]
    if (lane < 32) ao[j] = a;
    float bA = lb[32 + j];
    float bB = lb[64 + j];
#pragma unroll 1
    for (int t = 1; t < Tt; ++t) {
      float bcur = bA; bA = bB;
      if (t + 2 < Tt) bB = lb[(size_t)(t + 2) * 32 + j];
#pragma unroll
      for (int i = 0; i < 32; ++i) z[i] = rdlane(a, i) + acol[i];  // a_i + A[i][j]
      float m = max32(z);
#pragma unroll
      for (int i = 0; i < 32; ++i) z[i] = __expf(z[i] - m);        // exact sub
      float S = npsum32(z);
      a = (__logf(S) + m) + bcur;        // ((log S + max) + logB[t]) as in ref
      if (lane < 32) ao[(size_t)t * 32 + j] = a;
    }
    // evidence = logsumexp(alpha[T-1])
#pragma unroll
    for (int i = 0; i < 32; ++i) z[i] = rdlane(a, i);
    float m = max32(z);
#pragma unroll
    for (int i = 0; i < 32; ++i) z[i] = __expf(z[i] - m);
    float S = npsum32(z);
    if (lane == 0) ev[b] = __logf(S) + m;
  } else {
    float arow[32];                      // A[j][i] for all i
#pragma unroll
    for (int i = 0; i < 32; ++i) arow[i] = logA[j * 32 + i];
    float* bo = bet + (size_t)b * Tt * 32;
    if (lane < 32) bo[(size_t)(Tt - 1) * 32 + j] = 0.f;
    float y = lb[(size_t)(Tt - 1) * 32 + j] + 0.f;   // (logB[T-1] + beta[T-1])
    float bA = lb[(size_t)(Tt - 2) * 32 + j];
    float bB = lb[(size_t)(Tt - 3) * 32 + j];
#pragma unroll 1
    for (int t = Tt - 2; t >= 0; --t) {
      float bcur = bA; bA = bB;
      if (t >= 2) bB = lb[(size_t)(t - 2) * 32 + j];
#pragma unroll
      for (int i = 0; i < 32; ++i) z[i] = arow[i] + rdlane(y, i);  // A[j][i] + y_i
      float m = max32(z);
#pragma unroll
      for (int i = 0; i < 32; ++i) z[i] = __expf(z[i] - m);
      float S = npsum32(z);
      float bv = __logf(S) + m;          // beta[t][j]
      if (lane < 32) bo[(size_t)t * 32 + j] = bv;
      y = bcur + bv;                     // (logB[t] + beta[t]) for next step
    }
  }
}

// ---------------- K5: gamma = (alpha + beta) - evidence, fp32 ----------------
__global__ void k_gamma(const float* __restrict__ ws, float* __restrict__ out) {
  size_t idx = (size_t)blockIdx.x * blockDim.x + threadIdx.x;
  if (idx >= (size_t)NB * Tt * 32) return;
  int b = (int)(idx >> 17);            // T*S = 131072
  float a  = out[idx];
  float bb = ws[OFF_BET + idx];
  float e  = ws[OFF_EV + b];
  out[idx] = (a + bb) - e;
}

extern "C" void kernel_launch(void* const* d_in, const int* in_sizes, int n_in,
                              void* d_out, int out_size, void* d_ws, size_t ws_size,
                              hipStream_t stream) {
  const float* x     = (const float*)d_in[0];
  const float* means = (const float*)d_in[1];
  const float* covs  = (const float*)d_in[2];
  const float* logA  = (const float*)d_in[3];
  const float* logpi = (const float*)d_in[4];
  float* ws  = (float*)d_ws;
  float* out = (float*)d_out;

  k_chol<<<dim3(32), dim3(64), 0, stream>>>(covs, means, ws);
  k_emis<<<dim3(4096), dim3(64), 0, stream>>>(x, ws, ws + OFF_LB);
  k_fb<<<dim3(32), dim3(64), 0, stream>>>(logA, logpi, ws, out);
  k_gamma<<<dim3(8192), dim3(256), 0, stream>>>(ws, out);
}

// Round 4
// 2488.760 us; speedup vs baseline: 1.2944x; 1.2944x over previous
//
#include <hip/hip_runtime.h>
#include <math.h>

#define Tt 4096
#define NB 16

#define CLN2PI 1.8378770664093453f   // ln(2*pi)

// ws layout (float offsets)
#define OFF_W    0         // 131072  W = L^-1 per state (row-major, upper zeros)
#define OFF_D    131072    // 2048    d = W*mu
#define OFF_CST  133120    // 32      F*ln2pi + logdet  (nats)
#define OFF_EV   133152    // 16      evidence per batch (fp32 nats)
#define OFF_LB   133184    // 2097152 logB nats [b][t][s]
#define OFF_BET  2230336   // 2097152 beta  nats [b][t][s]
// total 4327488 floats = 17.3 MB

__device__ __forceinline__ float rdlane(float x, int l) {
  return __int_as_float(__builtin_amdgcn_readlane(__float_as_int(x), l));
}

// ---------------- K2: per-state Cholesky, W = L^-1, d = W*mu, cst ----------------
__global__ __launch_bounds__(64) void k_chol(const float* __restrict__ covs,
                                             const float* __restrict__ means,
                                             float* __restrict__ ws) {
  __shared__ float Am[64][65];
  __shared__ float Wl[64][65];
  int s = blockIdx.x, j = threadIdx.x;
  for (int r = 0; r < 64; ++r) {
    Am[r][j] = covs[((size_t)s * 64 + r) * 64 + j];
    Wl[r][j] = 0.f;
  }
  __syncthreads();
  for (int k = 0; k < 64; ++k) {
    float diag = sqrtf(Am[k][k]);
    float col = (j > k) ? Am[j][k] / diag : 0.f;
    __syncthreads();
    if (j == k) Am[k][k] = diag;
    if (j > k)  Am[j][k] = col;
    __syncthreads();
    if (j > k) {
      for (int g = k + 1; g <= j; ++g) Am[j][g] -= col * Am[g][k];
    }
    __syncthreads();
  }
  {
    int c = j;
    Wl[c][c] = 1.0f / Am[c][c];
    for (int f = c + 1; f < 64; ++f) {
      float ssum = 0.f;
      for (int g = c; g < f; ++g) ssum += Am[f][g] * Wl[g][c];
      Wl[f][c] = -ssum / Am[f][f];
    }
  }
  __syncthreads();
  for (int r = 0; r < 64; ++r)
    ws[OFF_W + ((size_t)s * 64 + r) * 64 + j] = Wl[r][j];
  {
    float acc = 0.f;
    for (int g = 0; g < 64; ++g) acc += Wl[j][g] * means[s * 64 + g];
    ws[OFF_D + s * 64 + j] = acc;
  }
  if (j == 0) {
    float logdet = 0.f;
    for (int k = 0; k < 64; ++k) logdet += __logf(Am[k][k]);
    logdet *= 2.0f;
    ws[OFF_CST + s] = 64.0f * CLN2PI + logdet;
  }
}

// ---------------- K3: emission logB (nats) ----------------
__global__ __launch_bounds__(64) void k_emis(const float* __restrict__ x,
                                             const float* __restrict__ wsr,
                                             float* __restrict__ lb) {
  const float* W = wsr + OFF_W;
  const float* D = wsr + OFF_D;
  const float* C = wsr + OFF_CST;
  int bx = blockIdx.x;
  int sgrp = bx & 3;
  int pt = (bx >> 2) * 64 + threadIdx.x;
  const float* xr = x + (size_t)pt * 64;
  float xv[64];
#pragma unroll
  for (int c = 0; c < 16; ++c) {
    float4 q = ((const float4*)xr)[c];
    xv[4 * c + 0] = q.x; xv[4 * c + 1] = q.y;
    xv[4 * c + 2] = q.z; xv[4 * c + 3] = q.w;
  }
#pragma unroll 1
  for (int si = 0; si < 8; ++si) {
    int s = sgrp * 8 + si;
    const float* Ws = W + (size_t)s * 4096;
    const float* Ds = D + s * 64;
    float maha = 0.f;
#pragma unroll
    for (int f = 0; f < 64; ++f) {
      float z = -Ds[f];
#pragma unroll
      for (int ch = 0; ch < 4; ++ch) {
        if (ch <= (f >> 4)) {
#pragma unroll
          for (int gg = 0; gg < 16; ++gg) {
            int g = ch * 16 + gg;
            z = fmaf(Ws[f * 64 + g], xv[g], z);
          }
        }
      }
      maha = fmaf(z, z, maha);
    }
    lb[(size_t)pt * 32 + s] = -0.5f * (maha + C[s]);
  }
}

// np-pairwise-order sum of 32 (matches numpy's 8-accumulator pairwise order)
__device__ __forceinline__ float npsum32(const float* z) {
  float r[8];
#pragma unroll
  for (int k = 0; k < 8; ++k)
    r[k] = ((z[k] + z[k + 8]) + z[k + 16]) + z[k + 24];
  return ((r[0] + r[1]) + (r[2] + r[3])) + ((r[4] + r[5]) + (r[6] + r[7]));
}
// exact max of 32 (order-independent, commutative -> any tree ok)
__device__ __forceinline__ float max32(const float* z) {
  float t16[16];
#pragma unroll
  for (int k = 0; k < 16; ++k) t16[k] = fmaxf(z[k], z[k + 16]);
  float t8[8];
#pragma unroll
  for (int k = 0; k < 8; ++k) t8[k] = fmaxf(t16[k], t16[k + 8]);
  float t4[4];
#pragma unroll
  for (int k = 0; k < 4; ++k) t4[k] = fmaxf(t8[k], t8[k + 4]);
  float t2a = fmaxf(t4[0], t4[2]), t2b = fmaxf(t4[1], t4[3]);
  return fmaxf(t2a, t2b);
}

// ---------------- K4: forward/backward, fp32 nats, np-matched ops ----------------
// 1 wave per (batch, dir). lane j (&31) owns state j; halves duplicate.
// launch_bounds(64,1)+waves_per_eu(1): 512-VGPR budget so acol/arow/z stay
// resident (R3's 40-VGPR allocation sank logA loads into the serial loop:
// 4.16 GB FETCH_SIZE, ~1600 cyc/step).
__global__ __launch_bounds__(64, 1) __attribute__((amdgpu_waves_per_eu(1)))
void k_fb(const float* __restrict__ logA,
          const float* __restrict__ logpi,
          float* __restrict__ ws,
          float* __restrict__ out) {
  const float* lbg = ws + OFF_LB;
  float* bet = ws + OFF_BET;
  float* ev  = ws + OFF_EV;
  int chain = blockIdx.x;
  int b   = chain & 15;
  int dir = chain >> 4;
  int lane = threadIdx.x;
  int j = lane & 31;
  const float* lb = lbg + (size_t)b * Tt * 32;
  float z[32];
  if (dir == 0) {
    float acol[32];                      // A[i][j] for all i — keep in VGPRs
#pragma unroll
    for (int i = 0; i < 32; ++i) {
      acol[i] = logA[i * 32 + j];
      asm volatile("" : "+v"(acol[i]));  // pin: no remat from memory
    }
    float* ao = out + (size_t)b * Tt * 32;
    float a = logpi[j] + lb[j];          // alpha[0]
    ao[j] = a;
    float bA = lb[32 + j];
    float bB = lb[64 + j];
    float bC = lb[96 + j];
#pragma unroll 1
    for (int t = 1; t < Tt; ++t) {
      float bcur = bA; bA = bB; bB = bC;
      if (t + 3 < Tt) bC = lb[(size_t)(t + 3) * 32 + j];
#pragma unroll
      for (int i = 0; i < 32; ++i) z[i] = rdlane(a, i) + acol[i];  // a_i + A[i][j]
      float m = max32(z);
#pragma unroll
      for (int i = 0; i < 32; ++i) z[i] = __expf(z[i] - m);        // exact sub
      float S = npsum32(z);
      a = (__logf(S) + m) + bcur;        // ((log S + max) + logB[t]) as in ref
      ao[(size_t)t * 32 + j] = a;        // halves write same value -> safe
    }
    // evidence = logsumexp(alpha[T-1])
#pragma unroll
    for (int i = 0; i < 32; ++i) z[i] = rdlane(a, i);
    float m = max32(z);
#pragma unroll
    for (int i = 0; i < 32; ++i) z[i] = __expf(z[i] - m);
    float S = npsum32(z);
    if (lane == 0) ev[b] = __logf(S) + m;
  } else {
    float arow[32];                      // A[j][i] for all i — keep in VGPRs
#pragma unroll
    for (int i = 0; i < 32; ++i) {
      arow[i] = logA[j * 32 + i];
      asm volatile("" : "+v"(arow[i]));
    }
    float* bo = bet + (size_t)b * Tt * 32;
    bo[(size_t)(Tt - 1) * 32 + j] = 0.f;
    float y = lb[(size_t)(Tt - 1) * 32 + j] + 0.f;   // (logB[T-1] + beta[T-1])
    float bA = lb[(size_t)(Tt - 2) * 32 + j];
    float bB = lb[(size_t)(Tt - 3) * 32 + j];
    float bC = lb[(size_t)(Tt - 4) * 32 + j];
#pragma unroll 1
    for (int t = Tt - 2; t >= 0; --t) {
      float bcur = bA; bA = bB; bB = bC;
      if (t >= 3) bC = lb[(size_t)(t - 3) * 32 + j];
#pragma unroll
      for (int i = 0; i < 32; ++i) z[i] = arow[i] + rdlane(y, i);  // A[j][i] + y_i
      float m = max32(z);
#pragma unroll
      for (int i = 0; i < 32; ++i) z[i] = __expf(z[i] - m);
      float S = npsum32(z);
      float bv = __logf(S) + m;          // beta[t][j]
      bo[(size_t)t * 32 + j] = bv;
      y = bcur + bv;                     // (logB[t] + beta[t]) for next step
    }
  }
}

// ---------------- K5: gamma = (alpha + beta) - evidence, fp32 ----------------
__global__ void k_gamma(const float* __restrict__ ws, float* __restrict__ out) {
  size_t idx = (size_t)blockIdx.x * blockDim.x + threadIdx.x;
  if (idx >= (size_t)NB * Tt * 32) return;
  int b = (int)(idx >> 17);            // T*S = 131072
  float a  = out[idx];
  float bb = ws[OFF_BET + idx];
  float e  = ws[OFF_EV + b];
  out[idx] = (a + bb) - e;
}

extern "C" void kernel_launch(void* const* d_in, const int* in_sizes, int n_in,
                              void* d_out, int out_size, void* d_ws, size_t ws_size,
                              hipStream_t stream) {
  const float* x     = (const float*)d_in[0];
  const float* means = (const float*)d_in[1];
  const float* covs  = (const float*)d_in[2];
  const float* logA  = (const float*)d_in[3];
  const float* logpi = (const float*)d_in[4];
  float* ws  = (float*)d_ws;
  float* out = (float*)d_out;

  k_chol<<<dim3(32), dim3(64), 0, stream>>>(covs, means, ws);
  k_emis<<<dim3(4096), dim3(64), 0, stream>>>(x, ws, ws + OFF_LB);
  k_fb<<<dim3(32), dim3(64), 0, stream>>>(logA, logpi, ws, out);
  k_gamma<<<dim3(8192), dim3(256), 0, stream>>>(ws, out);
}